// Round 1
// baseline (167.587 us; speedup 1.0000x reference)
//
#include <hip/hip_runtime.h>

#define D 50
#define HIDDEN 32

// ---------------------------------------------------------------------------
// Kernel 1: per-node projections.
//   P[n*64 + j]       = sum_k z[n][k] * W1[k][j]       + b1[j]   (src half)
//   P[n*64 + 32 + j]  = sum_k z[n][k] * W1[50+k][j]              (dst half)
// One wave (64 lanes) per node: lane c in [0,64) computes one output column.
// W1 is [100][32] row-major. Lanes 0..31 read column j of rows 0..49,
// lanes 32..63 read column j of rows 50..99 -> two coalesced 128B segments
// per k. z[n][k] is wave-uniform (L1 broadcast).
// ---------------------------------------------------------------------------
__global__ void node_proj_kernel(const float* __restrict__ z,
                                 const float* __restrict__ W1,
                                 const float* __restrict__ b1,
                                 float* __restrict__ P,
                                 int n_nodes) {
    int tid  = blockIdx.x * blockDim.x + threadIdx.x;
    int node = tid >> 6;
    int c    = tid & 63;
    if (node >= n_nodes) return;

    int j    = c & 31;
    int half = c >> 5;                       // 0 = src part, 1 = dst part
    const float* w  = W1 + (size_t)(half * D) * HIDDEN + j;
    const float* zp = z + (size_t)node * D;

    float acc = half ? 0.0f : b1[j];
#pragma unroll
    for (int k = 0; k < D; ++k) {
        acc = fmaf(zp[k], w[(size_t)k * HIDDEN], acc);
    }
    P[(size_t)node * 64 + c] = acc;
}

// ---------------------------------------------------------------------------
// Kernel 2: per-edge fused add + relu + dot(W2) + b2.
// One thread per edge. Two contiguous 128B gathers from the P table
// (mostly L2/L3 resident: table is 25.6 MB).
// ---------------------------------------------------------------------------
__global__ void edge_mlp_kernel(const int* __restrict__ eidx,
                                const float* __restrict__ P,
                                const float* __restrict__ W2,
                                const float* __restrict__ b2,
                                float* __restrict__ out,
                                int n_edges) {
    int e = blockIdx.x * blockDim.x + threadIdx.x;
    if (e >= n_edges) return;

    int s = eidx[e];
    int d = eidx[n_edges + e];

    const float4* pa = (const float4*)(P + (size_t)s * 64);
    const float4* pb = (const float4*)(P + (size_t)d * 64 + 32);
    const float4* w2 = (const float4*)W2;

    float acc = b2[0];
#pragma unroll
    for (int q = 0; q < 8; ++q) {
        float4 a = pa[q];
        float4 b = pb[q];
        float4 w = w2[q];
        float h0 = fmaxf(a.x + b.x, 0.0f);
        float h1 = fmaxf(a.y + b.y, 0.0f);
        float h2 = fmaxf(a.z + b.z, 0.0f);
        float h3 = fmaxf(a.w + b.w, 0.0f);
        acc = fmaf(h0, w.x, acc);
        acc = fmaf(h1, w.y, acc);
        acc = fmaf(h2, w.z, acc);
        acc = fmaf(h3, w.w, acc);
    }
    out[e] = acc;
}

// ---------------------------------------------------------------------------
// Fallback (only if ws_size can't hold the 25.6 MB P table): direct per-edge
// full MLP. Slow but correct.
// ---------------------------------------------------------------------------
__global__ void edge_direct_kernel(const float* __restrict__ z,
                                   const int* __restrict__ eidx,
                                   const float* __restrict__ W1,
                                   const float* __restrict__ b1,
                                   const float* __restrict__ W2,
                                   const float* __restrict__ b2,
                                   float* __restrict__ out,
                                   int n_edges) {
    int e = blockIdx.x * blockDim.x + threadIdx.x;
    if (e >= n_edges) return;
    int s = eidx[e];
    int d = eidx[n_edges + e];
    const float* zs = z + (size_t)s * D;
    const float* zd = z + (size_t)d * D;
    float acc = b2[0];
    for (int j = 0; j < HIDDEN; ++j) {
        float h = b1[j];
        for (int k = 0; k < D; ++k) {
            h = fmaf(zs[k], W1[(size_t)k * HIDDEN + j], h);
            h = fmaf(zd[k], W1[(size_t)(D + k) * HIDDEN + j], h);
        }
        acc = fmaf(fmaxf(h, 0.0f), W2[j], acc);
    }
    out[e] = acc;
}

extern "C" void kernel_launch(void* const* d_in, const int* in_sizes, int n_in,
                              void* d_out, int out_size, void* d_ws, size_t ws_size,
                              hipStream_t stream) {
    const float* z    = (const float*)d_in[0];
    const int*   eidx = (const int*)d_in[1];
    const float* W1   = (const float*)d_in[2];
    const float* b1   = (const float*)d_in[3];
    const float* W2   = (const float*)d_in[4];
    const float* b2   = (const float*)d_in[5];
    float*       out  = (float*)d_out;

    const int n_nodes = in_sizes[0] / D;          // 100000
    const int n_edges = in_sizes[1] / 2;          // 2000000

    const size_t p_bytes = (size_t)n_nodes * 64 * sizeof(float);

    if (p_bytes <= ws_size) {
        float* P = (float*)d_ws;

        // Kernel 1: one wave per node, 4 nodes per 256-thread block.
        int total1  = n_nodes * 64;
        int blocks1 = (total1 + 255) / 256;
        node_proj_kernel<<<blocks1, 256, 0, stream>>>(z, W1, b1, P, n_nodes);

        // Kernel 2: one thread per edge.
        int blocks2 = (n_edges + 255) / 256;
        edge_mlp_kernel<<<blocks2, 256, 0, stream>>>(eidx, P, W2, b2, out, n_edges);
    } else {
        int blocks = (n_edges + 255) / 256;
        edge_direct_kernel<<<blocks, 256, 0, stream>>>(z, eidx, W1, b1, W2, b2,
                                                       out, n_edges);
    }
}

// Round 3
// 119.243 us; speedup vs baseline: 1.4054x; 1.4054x over previous
//
#include <hip/hip_runtime.h>
#include <hip/hip_fp16.h>

#define D 50
#define HIDDEN 32
#define NPW 16   // nodes per wave in node_proj

// ---------------------------------------------------------------------------
// Kernel 1: per-node projections -> fp16 table P[n][64]
//   P[n][j]    = sum_k z[n][k] * W1[k][j]      + b1[j]   (cols 0..31, src half)
//   P[n][32+j] = sum_k z[n][k] * W1[50+k][j]             (cols 32..63, dst half)
//
// Lane c (0..63) owns one output column; its 50 W1-column values live in
// registers (loaded once, coalesced). The wave iterates NPW nodes; each z row
// is read as 25 wave-uniform broadcast float2 loads. Store: lanes pair up via
// shfl_xor and even lanes write packed __half2 (4-byte stores only -> one
// coalesced 128B burst per node; no sub-word global stores).
// ---------------------------------------------------------------------------
__global__ __launch_bounds__(256) void node_proj_kernel(
        const float* __restrict__ z,
        const float* __restrict__ W1,
        const float* __restrict__ b1,
        __half2* __restrict__ P2,      // P viewed as half2[n_nodes][32]
        int n_nodes) {
    int lane = threadIdx.x & 63;
    int wid  = (blockIdx.x * blockDim.x + threadIdx.x) >> 6;

    int j    = lane & 31;
    int half = lane >> 5;

    // Per-lane W1 column in registers.
    float Breg[D];
    const float* wcol = W1 + (size_t)(half * D) * HIDDEN + j;
#pragma unroll
    for (int k = 0; k < D; ++k) Breg[k] = wcol[(size_t)k * HIDDEN];

    float bias = half ? 0.0f : b1[j];

    int n0   = wid * NPW;
    int nend = n0 + NPW;
    if (nend > n_nodes) nend = n_nodes;

    for (int n = n0; n < nend; ++n) {
        const float2* zr = (const float2*)(z + (size_t)n * D);  // 8B aligned
        float acc = bias;
#pragma unroll
        for (int q = 0; q < D / 2; ++q) {
            float2 zq = zr[q];                // wave-uniform broadcast
            acc = fmaf(zq.x, Breg[2 * q],     acc);
            acc = fmaf(zq.y, Breg[2 * q + 1], acc);
        }
        // Pack columns (2t, 2t+1) in even lane 2t; 4-byte coalesced stores.
        float nb = __shfl_xor(acc, 1);
        if ((lane & 1) == 0) {
            P2[(size_t)n * 32 + (lane >> 1)] = __floats2half2_rn(acc, nb);
        }
    }
}

// ---------------------------------------------------------------------------
// Kernel 2: per-edge fused add + relu + dot(W2) + b2, fp16 gathers.
// One thread per edge: 4x16B src gather + 4x16B dst gather (64B + 64B).
// ---------------------------------------------------------------------------
__global__ void edge_mlp_kernel(const int* __restrict__ eidx,
                                const __half* __restrict__ P,
                                const float* __restrict__ W2,
                                const float* __restrict__ b2,
                                float* __restrict__ out,
                                int n_edges) {
    int e = blockIdx.x * blockDim.x + threadIdx.x;
    if (e >= n_edges) return;

    int s = eidx[e];
    int d = eidx[n_edges + e];

    const uint4* pa = (const uint4*)(P + (size_t)s * 64);        // cols 0..31
    const uint4* pb = (const uint4*)(P + (size_t)d * 64 + 32);   // cols 32..63
    const float4* w2 = (const float4*)W2;

    float acc = b2[0];
#pragma unroll
    for (int q = 0; q < 4; ++q) {           // 8 hidden units per iteration
        uint4 ua = pa[q];
        uint4 ub = pb[q];
        float4 w0 = w2[2 * q];
        float4 w1 = w2[2 * q + 1];

        float2 a0 = __half22float2(*(const __half2*)&ua.x);
        float2 a1 = __half22float2(*(const __half2*)&ua.y);
        float2 a2 = __half22float2(*(const __half2*)&ua.z);
        float2 a3 = __half22float2(*(const __half2*)&ua.w);
        float2 b0 = __half22float2(*(const __half2*)&ub.x);
        float2 b1v = __half22float2(*(const __half2*)&ub.y);
        float2 b2v = __half22float2(*(const __half2*)&ub.z);
        float2 b3 = __half22float2(*(const __half2*)&ub.w);

        acc = fmaf(fmaxf(a0.x + b0.x,  0.0f), w0.x, acc);
        acc = fmaf(fmaxf(a0.y + b0.y,  0.0f), w0.y, acc);
        acc = fmaf(fmaxf(a1.x + b1v.x, 0.0f), w0.z, acc);
        acc = fmaf(fmaxf(a1.y + b1v.y, 0.0f), w0.w, acc);
        acc = fmaf(fmaxf(a2.x + b2v.x, 0.0f), w1.x, acc);
        acc = fmaf(fmaxf(a2.y + b2v.y, 0.0f), w1.y, acc);
        acc = fmaf(fmaxf(a3.x + b3.x,  0.0f), w1.z, acc);
        acc = fmaf(fmaxf(a3.y + b3.y,  0.0f), w1.w, acc);
    }
    out[e] = acc;
}

// ---------------------------------------------------------------------------
// Fallback (ws too small): direct per-edge full MLP. Slow but correct.
// ---------------------------------------------------------------------------
__global__ void edge_direct_kernel(const float* __restrict__ z,
                                   const int* __restrict__ eidx,
                                   const float* __restrict__ W1,
                                   const float* __restrict__ b1,
                                   const float* __restrict__ W2,
                                   const float* __restrict__ b2,
                                   float* __restrict__ out,
                                   int n_edges) {
    int e = blockIdx.x * blockDim.x + threadIdx.x;
    if (e >= n_edges) return;
    int s = eidx[e];
    int d = eidx[n_edges + e];
    const float* zs = z + (size_t)s * D;
    const float* zd = z + (size_t)d * D;
    float acc = b2[0];
    for (int j = 0; j < HIDDEN; ++j) {
        float h = b1[j];
        for (int k = 0; k < D; ++k) {
            h = fmaf(zs[k], W1[(size_t)k * HIDDEN + j], h);
            h = fmaf(zd[k], W1[(size_t)(D + k) * HIDDEN + j], h);
        }
        acc = fmaf(fmaxf(h, 0.0f), W2[j], acc);
    }
    out[e] = acc;
}

extern "C" void kernel_launch(void* const* d_in, const int* in_sizes, int n_in,
                              void* d_out, int out_size, void* d_ws, size_t ws_size,
                              hipStream_t stream) {
    const float* z    = (const float*)d_in[0];
    const int*   eidx = (const int*)d_in[1];
    const float* W1   = (const float*)d_in[2];
    const float* b1   = (const float*)d_in[3];
    const float* W2   = (const float*)d_in[4];
    const float* b2   = (const float*)d_in[5];
    float*       out  = (float*)d_out;

    const int n_nodes = in_sizes[0] / D;          // 100000
    const int n_edges = in_sizes[1] / 2;          // 2000000

    const size_t p_bytes = (size_t)n_nodes * 64 * sizeof(__half);

    if (p_bytes <= ws_size) {
        __half* P = (__half*)d_ws;

        // Kernel 1: one wave per NPW nodes.
        int n_waves  = (n_nodes + NPW - 1) / NPW;
        int blocks1  = (n_waves * 64 + 255) / 256;
        node_proj_kernel<<<blocks1, 256, 0, stream>>>(z, W1, b1, (__half2*)P,
                                                      n_nodes);

        // Kernel 2: one thread per edge.
        int blocks2 = (n_edges + 255) / 256;
        edge_mlp_kernel<<<blocks2, 256, 0, stream>>>(eidx, P, W2, b2, out, n_edges);
    } else {
        int blocks = (n_edges + 255) / 256;
        edge_direct_kernel<<<blocks, 256, 0, stream>>>(z, eidx, W1, b1, W2, b2,
                                                       out, n_edges);
    }
}

// Round 4
// 89.385 us; speedup vs baseline: 1.8749x; 1.3340x over previous
//
#include <hip/hip_runtime.h>
#include <hip/hip_fp16.h>

#define D 50
#define HIDDEN 32
#define NB 64    // nodes per block in node_proj

// ---------------------------------------------------------------------------
// Kernel 1: per-node projections -> fp16 table P[n][64]
//   P[n][j]    = sum_k z[n][k] * W1[k][j]      + b1[j]   (cols 0..31, src half)
//   P[n][32+j] = sum_k z[n][k] * W1[50+k][j]             (cols 32..63, dst half)
//
// Block = 256 threads = 4 waves, handles NB=64 contiguous nodes.
// Phase 1: cooperative coalesced float4 load of the block's z rows into LDS
//          (64 x 200B = 12.8 KB, contiguous in z).
// Phase 2: lane c owns output column c; its 50 W1-column values are held in
//          registers (launch_bounds(256,4) -> 128 VGPR budget so Breg stays
//          resident). Each wave computes 16 nodes, reading z from LDS via
//          broadcast ds_read_b64 (no global-miss latency in the inner loop).
// Store: lanes pair via shfl_xor, even lanes write packed __half2 (4B stores).
// ---------------------------------------------------------------------------
__global__ __launch_bounds__(256, 4) void node_proj_kernel(
        const float* __restrict__ z,
        const float* __restrict__ W1,
        const float* __restrict__ b1,
        __half2* __restrict__ P2,      // P viewed as half2[n_nodes][32]
        int n_nodes) {
    __shared__ float zs[NB * D];       // 12.8 KB

    const int tid  = threadIdx.x;
    const int base = blockIdx.x * NB;
    int nloc = n_nodes - base;
    if (nloc > NB) nloc = NB;

    // ---- Phase 1: stage z rows (contiguous, coalesced) ----
    const int nf  = nloc * D;
    const int nf4 = nf >> 2;
    const float4* src4 = (const float4*)(z + (size_t)base * D);  // base*200 B, 16B-aligned (base % 64 == 0 except moot last block)
    float4* dst4 = (float4*)zs;
    for (int i = tid; i < nf4; i += 256) dst4[i] = src4[i];
    for (int i = (nf4 << 2) + tid; i < nf; i += 256) zs[i] = z[(size_t)base * D + i];
    __syncthreads();

    // ---- Per-lane W1 column in registers ----
    const int lane = tid & 63;
    const int wv   = tid >> 6;               // wave 0..3
    const int j    = lane & 31;
    const int half = lane >> 5;

    float Breg[D];
    const float* wcol = W1 + (size_t)(half * D) * HIDDEN + j;
#pragma unroll
    for (int k = 0; k < D; ++k) Breg[k] = wcol[(size_t)k * HIDDEN];

    const float bias = half ? 0.0f : b1[j];

    // ---- Phase 2: each wave computes 16 nodes ----
    int nlo = wv * 16;
    int nhi = nlo + 16;
    if (nhi > nloc) nhi = nloc;

    for (int nl = nlo; nl < nhi; ++nl) {
        const float2* zr = (const float2*)(zs + nl * D);   // 8B-aligned (nl*200)
        float acc = bias;
#pragma unroll
        for (int q = 0; q < D / 2; ++q) {
            float2 zq = zr[q];                             // broadcast ds_read_b64
            acc = fmaf(zq.x, Breg[2 * q],     acc);
            acc = fmaf(zq.y, Breg[2 * q + 1], acc);
        }
        float nb2 = __shfl_xor(acc, 1);
        if ((lane & 1) == 0) {
            P2[(size_t)(base + nl) * 32 + (lane >> 1)] = __floats2half2_rn(acc, nb2);
        }
    }
}

// ---------------------------------------------------------------------------
// Kernel 2: per-edge fused add + relu + dot(W2) + b2, fp16 gathers.
// One thread per edge: 4x16B src gather + 4x16B dst gather (64B + 64B, each
// half exactly one cacheline -> 100% line utilization).
// ---------------------------------------------------------------------------
__global__ void edge_mlp_kernel(const int* __restrict__ eidx,
                                const __half* __restrict__ P,
                                const float* __restrict__ W2,
                                const float* __restrict__ b2,
                                float* __restrict__ out,
                                int n_edges) {
    int e = blockIdx.x * blockDim.x + threadIdx.x;
    if (e >= n_edges) return;

    int s = eidx[e];
    int d = eidx[n_edges + e];

    const uint4* pa = (const uint4*)(P + (size_t)s * 64);        // cols 0..31
    const uint4* pb = (const uint4*)(P + (size_t)d * 64 + 32);   // cols 32..63
    const float4* w2 = (const float4*)W2;

    float acc = b2[0];
#pragma unroll
    for (int q = 0; q < 4; ++q) {           // 8 hidden units per iteration
        uint4 ua = pa[q];
        uint4 ub = pb[q];
        float4 w0 = w2[2 * q];
        float4 w1 = w2[2 * q + 1];

        float2 a0 = __half22float2(*(const __half2*)&ua.x);
        float2 a1 = __half22float2(*(const __half2*)&ua.y);
        float2 a2 = __half22float2(*(const __half2*)&ua.z);
        float2 a3 = __half22float2(*(const __half2*)&ua.w);
        float2 b0 = __half22float2(*(const __half2*)&ub.x);
        float2 b1v = __half22float2(*(const __half2*)&ub.y);
        float2 b2v = __half22float2(*(const __half2*)&ub.z);
        float2 b3 = __half22float2(*(const __half2*)&ub.w);

        acc = fmaf(fmaxf(a0.x + b0.x,  0.0f), w0.x, acc);
        acc = fmaf(fmaxf(a0.y + b0.y,  0.0f), w0.y, acc);
        acc = fmaf(fmaxf(a1.x + b1v.x, 0.0f), w0.z, acc);
        acc = fmaf(fmaxf(a1.y + b1v.y, 0.0f), w0.w, acc);
        acc = fmaf(fmaxf(a2.x + b2v.x, 0.0f), w1.x, acc);
        acc = fmaf(fmaxf(a2.y + b2v.y, 0.0f), w1.y, acc);
        acc = fmaf(fmaxf(a3.x + b3.x,  0.0f), w1.z, acc);
        acc = fmaf(fmaxf(a3.y + b3.y,  0.0f), w1.w, acc);
    }
    out[e] = acc;
}

// ---------------------------------------------------------------------------
// Fallback (ws too small): direct per-edge full MLP. Slow but correct.
// ---------------------------------------------------------------------------
__global__ void edge_direct_kernel(const float* __restrict__ z,
                                   const int* __restrict__ eidx,
                                   const float* __restrict__ W1,
                                   const float* __restrict__ b1,
                                   const float* __restrict__ W2,
                                   const float* __restrict__ b2,
                                   float* __restrict__ out,
                                   int n_edges) {
    int e = blockIdx.x * blockDim.x + threadIdx.x;
    if (e >= n_edges) return;
    int s = eidx[e];
    int d = eidx[n_edges + e];
    const float* zs = z + (size_t)s * D;
    const float* zd = z + (size_t)d * D;
    float acc = b2[0];
    for (int j = 0; j < HIDDEN; ++j) {
        float h = b1[j];
        for (int k = 0; k < D; ++k) {
            h = fmaf(zs[k], W1[(size_t)k * HIDDEN + j], h);
            h = fmaf(zd[k], W1[(size_t)(D + k) * HIDDEN + j], h);
        }
        acc = fmaf(fmaxf(h, 0.0f), W2[j], acc);
    }
    out[e] = acc;
}

extern "C" void kernel_launch(void* const* d_in, const int* in_sizes, int n_in,
                              void* d_out, int out_size, void* d_ws, size_t ws_size,
                              hipStream_t stream) {
    const float* z    = (const float*)d_in[0];
    const int*   eidx = (const int*)d_in[1];
    const float* W1   = (const float*)d_in[2];
    const float* b1   = (const float*)d_in[3];
    const float* W2   = (const float*)d_in[4];
    const float* b2   = (const float*)d_in[5];
    float*       out  = (float*)d_out;

    const int n_nodes = in_sizes[0] / D;          // 100000
    const int n_edges = in_sizes[1] / 2;          // 2000000

    const size_t p_bytes = (size_t)n_nodes * 64 * sizeof(__half);

    if (p_bytes <= ws_size) {
        __half* P = (__half*)d_ws;

        // Kernel 1: one block (4 waves) per NB nodes.
        int blocks1 = (n_nodes + NB - 1) / NB;
        node_proj_kernel<<<blocks1, 256, 0, stream>>>(z, W1, b1, (__half2*)P,
                                                      n_nodes);

        // Kernel 2: one thread per edge.
        int blocks2 = (n_edges + 255) / 256;
        edge_mlp_kernel<<<blocks2, 256, 0, stream>>>(eidx, P, W2, b2, out, n_edges);
    } else {
        int blocks = (n_edges + 255) / 256;
        edge_direct_kernel<<<blocks, 256, 0, stream>>>(z, eidx, W1, b1, W2, b2,
                                                       out, n_edges);
    }
}

// Round 5
// 76.497 us; speedup vs baseline: 2.1908x; 1.1685x over previous
//
#include <hip/hip_runtime.h>
#include <hip/hip_fp16.h>

#define D 50
#define HIDDEN 32
#define NB 32            // nodes per block in node_proj (4 waves x 8 nodes)
#define ZROW 52          // padded LDS row stride in floats (208 B, 16B-aligned)

// ---------------------------------------------------------------------------
// Kernel 1: per-node projections -> fp16 table P[n][64]
//   P[n][j]    = sum_k z[n][k] * W1[k][j]      + b1[j]   (cols 0..31, src half)
//   P[n][32+j] = sum_k z[n][k] * W1[50+k][j]             (cols 32..63, dst half)
//
// Block = 256 threads = 4 waves, NB=32 contiguous nodes (8 per wave).
// z rows staged in LDS with padded stride 52 so the inner loop reads them as
// 12x ds_read_b128 + 1x ds_read_b64 (13 LDS instrs/node instead of 25 --
// the LDS pipe, shared by all resident waves of a CU, was the bottleneck).
// Lane c owns output column c; its 50 W1 values stay in registers
// (launch_bounds(256,4) -> 128 VGPR budget).
// ---------------------------------------------------------------------------
__global__ __launch_bounds__(256, 4) void node_proj_kernel(
        const float* __restrict__ z,
        const float* __restrict__ W1,
        const float* __restrict__ b1,
        __half2* __restrict__ P2,      // P viewed as half2[n_nodes][32]
        int n_nodes) {
    __shared__ float zs[NB * ZROW];    // 6.65 KB

    const int tid  = threadIdx.x;
    const int base = blockIdx.x * NB;
    int nloc = n_nodes - base;
    if (nloc > NB) nloc = NB;

    // ---- Phase 1: stage z rows (coalesced float2; row = i/25, col2 = i%25) ----
    const float2* src2 = (const float2*)(z + (size_t)base * D);
    const int nf2 = nloc * (D / 2);
    for (int i = tid; i < nf2; i += 256) {
        int row  = i / 25;
        int col2 = i - row * 25;
        *(float2*)(zs + row * ZROW + col2 * 2) = src2[i];
    }
    __syncthreads();

    // ---- Per-lane W1 column in registers ----
    const int lane = tid & 63;
    const int wv   = tid >> 6;               // wave 0..3
    const int j    = lane & 31;
    const int half = lane >> 5;

    float Breg[D];
    const float* wcol = W1 + (size_t)(half * D) * HIDDEN + j;
#pragma unroll
    for (int k = 0; k < D; ++k) Breg[k] = wcol[(size_t)k * HIDDEN];

    const float bias = half ? 0.0f : b1[j];

    // ---- Phase 2: each wave computes 8 nodes via wide LDS broadcasts ----
    int nlo = wv * (NB / 4);
    int nhi = nlo + (NB / 4);
    if (nhi > nloc) nhi = nloc;

    for (int nl = nlo; nl < nhi; ++nl) {
        const float4* zr4 = (const float4*)(zs + nl * ZROW);
        float acc = bias;
#pragma unroll
        for (int q = 0; q < 12; ++q) {       // cols 0..47
            float4 v = zr4[q];               // broadcast ds_read_b128
            acc = fmaf(v.x, Breg[4 * q],     acc);
            acc = fmaf(v.y, Breg[4 * q + 1], acc);
            acc = fmaf(v.z, Breg[4 * q + 2], acc);
            acc = fmaf(v.w, Breg[4 * q + 3], acc);
        }
        float2 t = *(const float2*)(zs + nl * ZROW + 48);  // cols 48,49
        acc = fmaf(t.x, Breg[48], acc);
        acc = fmaf(t.y, Breg[49], acc);

        float nb2 = __shfl_xor(acc, 1);
        if ((lane & 1) == 0) {
            P2[(size_t)(base + nl) * 32 + (lane >> 1)] = __floats2half2_rn(acc, nb2);
        }
    }
}

// ---------------------------------------------------------------------------
// Kernel 2: per-edge fused add + relu + dot(W2) + b2 -- 4 lanes per edge.
// Lane r = lane&3 handles hidden units [8r, 8r+8): one 16B src chunk + one
// 16B dst chunk. Lanes 0..3 read CONSECUTIVE 16B -> one 64B segment per
// group (2 L1 transactions/edge vs 8 before; same bytes). Group-sum via
// shfl_xor(1), shfl_xor(2); lane r==0 writes (16 consecutive floats/wave).
// ---------------------------------------------------------------------------
__global__ void edge_mlp_kernel(const int* __restrict__ eidx,
                                const __half* __restrict__ P,
                                const float* __restrict__ W2,
                                const float* __restrict__ b2,
                                float* __restrict__ out,
                                int n_edges) {
    int t = blockIdx.x * blockDim.x + threadIdx.x;
    int e = t >> 2;
    int r = t & 3;
    if (e >= n_edges) return;

    int s = eidx[e];
    int d = eidx[n_edges + e];

    uint4 ua = *(const uint4*)(P + (size_t)s * 64 + r * 8);        // src units 8r..8r+7
    uint4 ub = *(const uint4*)(P + (size_t)d * 64 + 32 + r * 8);   // dst units 8r..8r+7
    float4 w0 = *(const float4*)(W2 + r * 8);
    float4 w1 = *(const float4*)(W2 + r * 8 + 4);

    float2 a0 = __half22float2(*(const __half2*)&ua.x);
    float2 a1 = __half22float2(*(const __half2*)&ua.y);
    float2 a2 = __half22float2(*(const __half2*)&ua.z);
    float2 a3 = __half22float2(*(const __half2*)&ua.w);
    float2 b0 = __half22float2(*(const __half2*)&ub.x);
    float2 b1v = __half22float2(*(const __half2*)&ub.y);
    float2 b2v = __half22float2(*(const __half2*)&ub.z);
    float2 b3 = __half22float2(*(const __half2*)&ub.w);

    float acc = (r == 0) ? b2[0] : 0.0f;
    acc = fmaf(fmaxf(a0.x + b0.x,  0.0f), w0.x, acc);
    acc = fmaf(fmaxf(a0.y + b0.y,  0.0f), w0.y, acc);
    acc = fmaf(fmaxf(a1.x + b1v.x, 0.0f), w0.z, acc);
    acc = fmaf(fmaxf(a1.y + b1v.y, 0.0f), w0.w, acc);
    acc = fmaf(fmaxf(a2.x + b2v.x, 0.0f), w1.x, acc);
    acc = fmaf(fmaxf(a2.y + b2v.y, 0.0f), w1.y, acc);
    acc = fmaf(fmaxf(a3.x + b3.x,  0.0f), w1.z, acc);
    acc = fmaf(fmaxf(a3.y + b3.y,  0.0f), w1.w, acc);

    acc += __shfl_xor(acc, 1);
    acc += __shfl_xor(acc, 2);

    if (r == 0) out[e] = acc;
}

// ---------------------------------------------------------------------------
// Fallback (ws too small): direct per-edge full MLP. Slow but correct.
// ---------------------------------------------------------------------------
__global__ void edge_direct_kernel(const float* __restrict__ z,
                                   const int* __restrict__ eidx,
                                   const float* __restrict__ W1,
                                   const float* __restrict__ b1,
                                   const float* __restrict__ W2,
                                   const float* __restrict__ b2,
                                   float* __restrict__ out,
                                   int n_edges) {
    int e = blockIdx.x * blockDim.x + threadIdx.x;
    if (e >= n_edges) return;
    int s = eidx[e];
    int d = eidx[n_edges + e];
    const float* zs = z + (size_t)s * D;
    const float* zd = z + (size_t)d * D;
    float acc = b2[0];
    for (int j = 0; j < HIDDEN; ++j) {
        float h = b1[j];
        for (int k = 0; k < D; ++k) {
            h = fmaf(zs[k], W1[(size_t)k * HIDDEN + j], h);
            h = fmaf(zd[k], W1[(size_t)(D + k) * HIDDEN + j], h);
        }
        acc = fmaf(fmaxf(h, 0.0f), W2[j], acc);
    }
    out[e] = acc;
}

extern "C" void kernel_launch(void* const* d_in, const int* in_sizes, int n_in,
                              void* d_out, int out_size, void* d_ws, size_t ws_size,
                              hipStream_t stream) {
    const float* z    = (const float*)d_in[0];
    const int*   eidx = (const int*)d_in[1];
    const float* W1   = (const float*)d_in[2];
    const float* b1   = (const float*)d_in[3];
    const float* W2   = (const float*)d_in[4];
    const float* b2   = (const float*)d_in[5];
    float*       out  = (float*)d_out;

    const int n_nodes = in_sizes[0] / D;          // 100000
    const int n_edges = in_sizes[1] / 2;          // 2000000

    const size_t p_bytes = (size_t)n_nodes * 64 * sizeof(__half);

    if (p_bytes <= ws_size) {
        __half* P = (__half*)d_ws;

        // Kernel 1: one block (4 waves) per NB nodes.
        int blocks1 = (n_nodes + NB - 1) / NB;
        node_proj_kernel<<<blocks1, 256, 0, stream>>>(z, W1, b1, (__half2*)P,
                                                      n_nodes);

        // Kernel 2: 4 threads per edge.
        long long total2 = (long long)n_edges * 4;
        int blocks2 = (int)((total2 + 255) / 256);
        edge_mlp_kernel<<<blocks2, 256, 0, stream>>>(eidx, P, W2, b2, out, n_edges);
    } else {
        int blocks = (n_edges + 255) / 256;
        edge_direct_kernel<<<blocks, 256, 0, stream>>>(z, eidx, W1, b1, W2, b2,
                                                       out, n_edges);
    }
}